// Round 4
// baseline (1669.308 us; speedup 1.0000x reference)
//
#include <hip/hip_runtime.h>
#include <hip/hip_bf16.h>

#define DIM 128
#define G4 512      // 4*DIM
#define NL 4
#define VOCAB 32000
#define BB 32
#define SS 256
#define ROWS (BB*SS)   // 8192

typedef __attribute__((ext_vector_type(8))) short short8;
typedef __attribute__((ext_vector_type(4))) float f32x4;

__device__ __forceinline__ float fexp_(float x){ return __builtin_amdgcn_exp2f(x * 1.44269504088896f); }
__device__ __forceinline__ float frcp_(float x){ return __builtin_amdgcn_rcpf(x); }
__device__ __forceinline__ float sigm_(float x){ return frcp_(1.f + fexp_(-x)); }
__device__ __forceinline__ float tanh_(float x){
    float ax = fabsf(x);
    float e = fexp_(-2.f * ax);
    float t = (1.f - e) * frcp_(1.f + e);
    return x < 0.f ? -t : t;
}

// 32 NAMED float4 weight registers (128 VGPRs) — named scalars are reliably
// register-allocated; the float4 w[32] array version spilled (VGPR_Count=84,
// round-3 counters) and re-loaded weights every timestep.
#define W_DECL_ALL \
    float4 w0,w1,w2,w3,w4,w5,w6,w7,w8,w9,w10,w11,w12,w13,w14,w15, \
           w16,w17,w18,w19,w20,w21,w22,w23,w24,w25,w26,w27,w28,w29,w30,w31;
#define W_LOAD(i) w##i = wr[i];
#define W_LOAD_ALL \
    W_LOAD(0) W_LOAD(1) W_LOAD(2) W_LOAD(3) W_LOAD(4) W_LOAD(5) W_LOAD(6) W_LOAD(7) \
    W_LOAD(8) W_LOAD(9) W_LOAD(10) W_LOAD(11) W_LOAD(12) W_LOAD(13) W_LOAD(14) W_LOAD(15) \
    W_LOAD(16) W_LOAD(17) W_LOAD(18) W_LOAD(19) W_LOAD(20) W_LOAD(21) W_LOAD(22) W_LOAD(23) \
    W_LOAD(24) W_LOAD(25) W_LOAD(26) W_LOAD(27) W_LOAD(28) W_LOAD(29) W_LOAD(30) W_LOAD(31)
#define FMA1(i, acc) acc = fmaf(h4[i].x, w##i.x, fmaf(h4[i].y, w##i.y, \
                      fmaf(h4[i].z, w##i.z, fmaf(h4[i].w, w##i.w, acc))));
// 4 independent chains of 8 (dep depth 8*4=32cy, hidden across waves)
#define DOT128(a0,a1,a2,a3) \
    FMA1(0,a0) FMA1(1,a0) FMA1(2,a0) FMA1(3,a0) FMA1(4,a0) FMA1(5,a0) FMA1(6,a0) FMA1(7,a0) \
    FMA1(8,a1) FMA1(9,a1) FMA1(10,a1) FMA1(11,a1) FMA1(12,a1) FMA1(13,a1) FMA1(14,a1) FMA1(15,a1) \
    FMA1(16,a2) FMA1(17,a2) FMA1(18,a2) FMA1(19,a2) FMA1(20,a2) FMA1(21,a2) FMA1(22,a2) FMA1(23,a2) \
    FMA1(24,a3) FMA1(25,a3) FMA1(26,a3) FMA1(27,a3) FMA1(28,a3) FMA1(29,a3) FMA1(30,a3) FMA1(31,a3)

// ---------------- K1: embedding gather ----------------
__global__ void k_embed(const int* __restrict__ x, const float* __restrict__ emb,
                        float* __restrict__ hseq){
    int i = blockIdx.x * blockDim.x + threadIdx.x;
    int row = i >> 5;
    int d4  = i & 31;
    int tok = x[row];
    ((float4*)hseq)[i] = ((const float4*)emb)[tok * 32 + d4];
}

// ---------------- K2: xw = hseq @ Wih^T + bih + bhh ----------------
__global__ __launch_bounds__(512, 2) void k_xw(const float* __restrict__ hseq,
                                               const float* __restrict__ Wih,
                                               const float* __restrict__ bih,
                                               const float* __restrict__ bhh,
                                               float* __restrict__ xw){
    __shared__ float hs[32 * DIM];
    int g = threadIdx.x;
    int r0 = blockIdx.x * 32;
    {
        const float4* src = (const float4*)(hseq + (size_t)r0 * DIM);
        float4* dst = (float4*)hs;
        for (int j = g; j < 32 * 32; j += 512) dst[j] = src[j];
    }
    const float4* wr = (const float4*)(Wih + (size_t)g * DIM);
    W_DECL_ALL
    W_LOAD_ALL
    float bias = bih[g] + bhh[g];
    __syncthreads();
    for (int r = 0; r < 32; ++r){
        const float4* h4 = (const float4*)(hs + r * DIM);
        float a0 = bias, a1 = 0.f, a2 = 0.f, a3 = 0.f;
        DOT128(a0, a1, a2, a3)
        xw[(size_t)(r0 + r) * G4 + g] = (a0 + a1) + (a2 + a3);
    }
}

// ---------------- K3: LSTM scan for one layer ----------------
// 32 blocks (one per batch) x 512 threads; thread g holds Whh row g in 32 named
// float4 registers. hseq is updated in place (read by next layer's k_xw / k_ln).
__global__ __launch_bounds__(512, 2) void k_scan(const float* __restrict__ xw,
                                                 const float* __restrict__ Whh,
                                                 float* __restrict__ hseq){
    __shared__ float hbuf[2][DIM];
    __shared__ float gates[G4];
    int g = threadIdx.x;
    int b = blockIdx.x;
    const float4* wr = (const float4*)(Whh + (size_t)g * DIM);
    W_DECL_ALL
    W_LOAD_ALL
    float c = 0.f;
    if (g < DIM) hbuf[0][g] = 0.f;
    const float* xwb = xw + (size_t)b * SS * G4;
    float* hout = hseq + (size_t)b * SS * DIM;
    float xr = xwb[g];
    __syncthreads();
    int p = 0;
    for (int t = 0; t < SS; ++t){
        float xn = 0.f;
        if (t + 1 < SS) xn = xwb[(size_t)(t + 1) * G4 + g];  // prefetch next (L2)
        const float4* h4 = (const float4*)hbuf[p];
        float a0 = xr, a1 = 0.f, a2 = 0.f, a3 = 0.f;
        DOT128(a0, a1, a2, a3)
        gates[g] = (a0 + a1) + (a2 + a3);
        __syncthreads();
        if (g < DIM){
            float iv = sigm_(gates[g]);
            float fv = sigm_(gates[DIM + g]);
            float gv = tanh_(gates[2 * DIM + g]);
            float ov = sigm_(gates[3 * DIM + g]);
            c = fv * c + iv * gv;
            float h = ov * tanh_(c);
            hbuf[p ^ 1][g] = h;
            hout[(size_t)t * DIM + g] = h;
        }
        __syncthreads();
        xr = xn; p ^= 1;
    }
}

// ---------------- K4: LayerNorm -> bf16 ----------------
__global__ void k_ln(const float* __restrict__ hseq, const float* __restrict__ gamma,
                     const float* __restrict__ beta, __hip_bfloat16* __restrict__ hn){
    int wid = threadIdx.x >> 6;
    int lane = threadIdx.x & 63;
    int row = blockIdx.x * 4 + wid;
    float2 hv = ((const float2*)(hseq + (size_t)row * DIM))[lane];
    float s = hv.x + hv.y;
    float sq = fmaf(hv.x, hv.x, hv.y * hv.y);
    for (int off = 32; off; off >>= 1){ s += __shfl_xor(s, off); sq += __shfl_xor(sq, off); }
    float mu = s * (1.f / 128.f);
    float var = sq * (1.f / 128.f) - mu * mu;
    float inv = rsqrtf(var + 1e-5f);
    float2 gv = ((const float2*)gamma)[lane];
    float2 bv = ((const float2*)beta)[lane];
    __hip_bfloat162 pr;
    pr.x = __float2bfloat16((hv.x - mu) * inv * gv.x + bv.x);
    pr.y = __float2bfloat16((hv.y - mu) * inv * gv.y + bv.y);
    ((__hip_bfloat162*)hn)[(size_t)row * 64 + lane] = pr;
}

// ---------------- K5: head_W fp32 -> bf16 ----------------
__global__ void k_cvt(const float* __restrict__ w, __hip_bfloat16* __restrict__ wb){
    int i = blockIdx.x * blockDim.x + threadIdx.x;
    float4 v = ((const float4*)w)[i];
    __hip_bfloat162 p0, p1;
    p0.x = __float2bfloat16(v.x); p0.y = __float2bfloat16(v.y);
    p1.x = __float2bfloat16(v.z); p1.y = __float2bfloat16(v.w);
    ((__hip_bfloat162*)wb)[2 * i]     = p0;
    ((__hip_bfloat162*)wb)[2 * i + 1] = p1;
}

// ---------------- K6: head GEMM (bf16 MFMA, swapped operands, float4 stores) ----
__global__ __launch_bounds__(256) void k_head(const __hip_bfloat16* __restrict__ hn,
                                              const __hip_bfloat16* __restrict__ wb,
                                              const float* __restrict__ head_b,
                                              float* __restrict__ out){
    int bn = blockIdx.x;
    int bm = blockIdx.y;
    int wid = threadIdx.x >> 6;
    int lane = threadIdx.x & 63;
    int wr = wid >> 1, wc = wid & 1;
    int row0 = bm * 128 + wr * 64;
    int col0 = bn * 128 + wc * 64;
    const short* A  = (const short*)hn;   // [8192][128]
    const short* Bp = (const short*)wb;   // [32000][128]
    f32x4 zero = {0.f, 0.f, 0.f, 0.f};
    f32x4 acc[4][4];   // [mi][ni]
#pragma unroll
    for (int i = 0; i < 4; ++i)
#pragma unroll
        for (int j = 0; j < 4; ++j) acc[i][j] = zero;
    int lrow = lane & 15;
    int kgr = (lane >> 4) * 8;
#pragma unroll
    for (int ks = 0; ks < 4; ++ks){
        short8 a[4], bf[4];
#pragma unroll
        for (int mi = 0; mi < 4; ++mi)
            a[mi] = *(const short8*)(A + (size_t)(row0 + mi * 16 + lrow) * DIM + ks * 32 + kgr);
#pragma unroll
        for (int ni = 0; ni < 4; ++ni)
            bf[ni] = *(const short8*)(Bp + (size_t)(col0 + ni * 16 + lrow) * DIM + ks * 32 + kgr);
#pragma unroll
        for (int mi = 0; mi < 4; ++mi)
#pragma unroll
            for (int ni = 0; ni < 4; ++ni)
                acc[mi][ni] = __builtin_amdgcn_mfma_f32_16x16x32_bf16(bf[ni], a[mi], acc[mi][ni], 0, 0, 0);
    }
    int csub = (lane >> 4) * 4;
#pragma unroll
    for (int ni = 0; ni < 4; ++ni){
        int cbase = col0 + ni * 16 + csub;
        float4 b4 = ((const float4*)head_b)[cbase >> 2];
#pragma unroll
        for (int mi = 0; mi < 4; ++mi){
            int row = row0 + mi * 16 + lrow;
            float4 v;
            v.x = acc[mi][ni][0] + b4.x;
            v.y = acc[mi][ni][1] + b4.y;
            v.z = acc[mi][ni][2] + b4.z;
            v.w = acc[mi][ni][3] + b4.w;
            *(float4*)(out + (size_t)row * VOCAB + cbase) = v;
        }
    }
}

extern "C" void kernel_launch(void* const* d_in, const int* in_sizes, int n_in,
                              void* d_out, int out_size, void* d_ws, size_t ws_size,
                              hipStream_t stream){
    const int*   x     = (const int*)  d_in[0];
    const float* emb   = (const float*)d_in[1];
    const float* Wih   = (const float*)d_in[2];
    const float* Whh   = (const float*)d_in[3];
    const float* bih   = (const float*)d_in[4];
    const float* bhh   = (const float*)d_in[5];
    const float* gamma = (const float*)d_in[6];
    const float* beta  = (const float*)d_in[7];
    const float* headW = (const float*)d_in[8];
    const float* headb = (const float*)d_in[9];
    float* out = (float*)d_out;

    char* ws = (char*)d_ws;
    float* xw   = (float*)ws;                                  // 16 MB [8192][512]
    float* hseq = (float*)(ws + (16u << 20));                  // 4 MB  [8192][128]
    __hip_bfloat16* hn = (__hip_bfloat16*)(ws + (20u << 20));  // 2 MB
    __hip_bfloat16* wb = (__hip_bfloat16*)(ws + (22u << 20));  // 8 MB

    k_embed<<<1024, 256, 0, stream>>>(x, emb, hseq);
    k_cvt  <<<4000, 256, 0, stream>>>(headW, wb);
    for (int l = 0; l < NL; ++l){
        k_xw  <<<256, 512, 0, stream>>>(hseq, Wih + (size_t)l * G4 * DIM,
                                        bih + l * G4, bhh + l * G4, xw);
        k_scan<<<32, 512, 0, stream>>>(xw, Whh + (size_t)l * G4 * DIM, hseq);
    }
    k_ln   <<<2048, 256, 0, stream>>>(hseq, gamma, beta, hn);
    k_head <<<dim3(250, 64), 256, 0, stream>>>(hn, wb, headb, out);
}

// Round 5
// 1444.055 us; speedup vs baseline: 1.1560x; 1.1560x over previous
//
#include <hip/hip_runtime.h>
#include <hip/hip_bf16.h>

#define DIM 128
#define G4 512      // 4*DIM
#define NL 4
#define VOCAB 32000
#define BB 32
#define SS 256
#define ROWS (BB*SS)   // 8192

typedef __attribute__((ext_vector_type(8))) short short8;
typedef __attribute__((ext_vector_type(4))) float f32x4;

__device__ __forceinline__ float fexp_(float x){ return __builtin_amdgcn_exp2f(x * 1.44269504088896f); }
__device__ __forceinline__ float frcp_(float x){ return __builtin_amdgcn_rcpf(x); }
__device__ __forceinline__ float sigm_(float x){ return frcp_(1.f + fexp_(-x)); }
__device__ __forceinline__ float tanh_(float x){
    float ax = fabsf(x);
    float e = fexp_(-2.f * ax);
    float t = (1.f - e) * frcp_(1.f + e);
    return x < 0.f ? -t : t;
}

#define FMA4(cv, wv, acc) acc = fmaf(cv.x, wv.x, fmaf(cv.y, wv.y, fmaf(cv.z, wv.z, fmaf(cv.w, wv.w, acc))));

// ---- per-gate 32-float weight block (8 float4, named regs) ----
#define WDECL(p) float4 p##0,p##1,p##2,p##3,p##4,p##5,p##6,p##7;
#define WLOAD(p, src) p##0=(src)[0]; p##1=(src)[1]; p##2=(src)[2]; p##3=(src)[3]; \
                      p##4=(src)[4]; p##5=(src)[5]; p##6=(src)[6]; p##7=(src)[7];
#define DOT32(p, acc) FMA4(c0,p##0,acc) FMA4(c1,p##1,acc) FMA4(c2,p##2,acc) FMA4(c3,p##3,acc) \
                      FMA4(c4,p##4,acc) FMA4(c5,p##5,acc) FMA4(c6,p##6,acc) FMA4(c7,p##7,acc)

// full-K (128) versions for k_xw (1 gate/thread, broadcast h)
#define W_DECL_ALL \
    float4 w0,w1,w2,w3,w4,w5,w6,w7,w8,w9,w10,w11,w12,w13,w14,w15, \
           w16,w17,w18,w19,w20,w21,w22,w23,w24,w25,w26,w27,w28,w29,w30,w31;
#define W_LOAD(i) w##i = wr[i];
#define W_LOAD_ALL \
    W_LOAD(0) W_LOAD(1) W_LOAD(2) W_LOAD(3) W_LOAD(4) W_LOAD(5) W_LOAD(6) W_LOAD(7) \
    W_LOAD(8) W_LOAD(9) W_LOAD(10) W_LOAD(11) W_LOAD(12) W_LOAD(13) W_LOAD(14) W_LOAD(15) \
    W_LOAD(16) W_LOAD(17) W_LOAD(18) W_LOAD(19) W_LOAD(20) W_LOAD(21) W_LOAD(22) W_LOAD(23) \
    W_LOAD(24) W_LOAD(25) W_LOAD(26) W_LOAD(27) W_LOAD(28) W_LOAD(29) W_LOAD(30) W_LOAD(31)
#define FMA1(i, acc) acc = fmaf(h4[i].x, w##i.x, fmaf(h4[i].y, w##i.y, \
                      fmaf(h4[i].z, w##i.z, fmaf(h4[i].w, w##i.w, acc))));
#define DOT128(a0,a1,a2,a3) \
    FMA1(0,a0) FMA1(1,a0) FMA1(2,a0) FMA1(3,a0) FMA1(4,a0) FMA1(5,a0) FMA1(6,a0) FMA1(7,a0) \
    FMA1(8,a1) FMA1(9,a1) FMA1(10,a1) FMA1(11,a1) FMA1(12,a1) FMA1(13,a1) FMA1(14,a1) FMA1(15,a1) \
    FMA1(16,a2) FMA1(17,a2) FMA1(18,a2) FMA1(19,a2) FMA1(20,a2) FMA1(21,a2) FMA1(22,a2) FMA1(23,a2) \
    FMA1(24,a3) FMA1(25,a3) FMA1(26,a3) FMA1(27,a3) FMA1(28,a3) FMA1(29,a3) FMA1(30,a3) FMA1(31,a3)

// ---------------- K1: embedding gather ----------------
__global__ void k_embed(const int* __restrict__ x, const float* __restrict__ emb,
                        float* __restrict__ hseq){
    int i = blockIdx.x * blockDim.x + threadIdx.x;
    int row = i >> 5;
    int d4  = i & 31;
    int tok = x[row];
    ((float4*)hseq)[i] = ((const float4*)emb)[tok * 32 + d4];
}

// ---------------- K2: xw = hseq @ Wih^T + bih + bhh (PERMUTED output) ----------
// Output layout per timestep row: idx = w*64 + g16*4 + p for gate g = w*64+p*16+g16,
// so k_scan loads one float4 per thread. Wih and xw are NON-restrict: stores via
// xw may alias Wih -> compiler cannot rematerialize weight loads inside the loop.
__global__ __launch_bounds__(512, 2) void k_xw(const float* __restrict__ hseq,
                                               const float* Wih,
                                               const float* __restrict__ bih,
                                               const float* __restrict__ bhh,
                                               float* xw){
    __shared__ float hs[32 * DIM];
    int g = threadIdx.x;
    int r0 = blockIdx.x * 32;
    {
        const float4* src = (const float4*)(hseq + (size_t)r0 * DIM);
        float4* dst = (float4*)hs;
        for (int j = g; j < 32 * 32; j += 512) dst[j] = src[j];
    }
    const float4* wr = (const float4*)(Wih + (size_t)g * DIM);
    W_DECL_ALL
    W_LOAD_ALL
    float bias = bih[g] + bhh[g];
    int w = g >> 6, p = (g >> 4) & 3, g16 = g & 15;
    int pidx = w * 64 + g16 * 4 + p;
    __syncthreads();
    for (int r = 0; r < 32; ++r){
        const float4* h4 = (const float4*)(hs + r * DIM);
        float a0 = bias, a1 = 0.f, a2 = 0.f, a3 = 0.f;
        DOT128(a0, a1, a2, a3)
        xw[(size_t)(r0 + r) * G4 + pidx] = (a0 + a1) + (a2 + a3);
    }
}

// ---------------- K3: LSTM scan, K-split layout ----------------
// 32 blocks (one per batch) x 512 threads. Lane = (g16 = lane&15, kg = lane>>4).
// Thread owns 4 gates {w*64 + p*16 + g16} x K-chunk [kg*32, kg*32+32) -> 128 weight
// floats in named VGPRs. h chunk (32 floats) read as 8 ds_read_b128 from padded LDS
// (chunk stride 36 floats -> conflict-free). Partial sums reduced via shfl_xor(16,32);
// each lane activates ONE gate (act[tid]); threads<128 do the cell update.
// Whh and hseq are NON-restrict (blocks weight-load remat; see round-4 post-mortem).
__global__ __launch_bounds__(512, 2) void k_scan(const float* __restrict__ xw,
                                                 const float* Whh,
                                                 float* hseq){
    __shared__ float hbuf[2][4 * 36];   // 4 chunks x (32 + 4 pad)
    __shared__ float act[G4];
    const int tid = threadIdx.x;
    const int b = blockIdx.x;
    const int w = tid >> 6;
    const int lane = tid & 63;
    const int g16 = lane & 15;
    const int kg = lane >> 4;

    WDECL(pA) WDECL(pB) WDECL(pC) WDECL(pD)
    {
        const float4* s0 = (const float4*)(Whh + (size_t)(w * 64 + 0 * 16 + g16) * DIM + kg * 32);
        const float4* s1 = (const float4*)(Whh + (size_t)(w * 64 + 1 * 16 + g16) * DIM + kg * 32);
        const float4* s2 = (const float4*)(Whh + (size_t)(w * 64 + 2 * 16 + g16) * DIM + kg * 32);
        const float4* s3 = (const float4*)(Whh + (size_t)(w * 64 + 3 * 16 + g16) * DIM + kg * 32);
        WLOAD(pA, s0) WLOAD(pB, s1) WLOAD(pC, s2) WLOAD(pD, s3)
    }
    const bool is_tanh = (w == 4 || w == 5);   // gates 256..383 = g-gate
    float c = 0.f;
    if (tid < 144) hbuf[0][tid] = 0.f;
    const float* xwb = xw + (size_t)b * SS * G4 + w * 64 + g16 * 4;
    float* hout = hseq + (size_t)b * SS * DIM;
    float4 xr = *(const float4*)xwb;
    __syncthreads();
    int p = 0;
    for (int t = 0; t < SS; ++t){
        float4 xn = {0.f,0.f,0.f,0.f};
        if (t + 1 < SS) xn = *(const float4*)(xwb + (size_t)(t + 1) * G4);   // prefetch (L2)
        // h chunk -> 8 float4 regs (conflict-free b128 reads)
        const float4* hc = (const float4*)(hbuf[p] + kg * 36);
        float4 c0 = hc[0], c1 = hc[1], c2 = hc[2], c3 = hc[3],
               c4 = hc[4], c5 = hc[5], c6 = hc[6], c7 = hc[7];
        float a0 = 0.f, a1 = 0.f, a2 = 0.f, a3 = 0.f;
        DOT32(pA, a0) DOT32(pB, a1) DOT32(pC, a2) DOT32(pD, a3)
        // reduce over kg (lanes differing in bits 4,5)
        a0 += __shfl_xor(a0, 16); a0 += __shfl_xor(a0, 32);
        a1 += __shfl_xor(a1, 16); a1 += __shfl_xor(a1, 32);
        a2 += __shfl_xor(a2, 16); a2 += __shfl_xor(a2, 32);
        a3 += __shfl_xor(a3, 16); a3 += __shfl_xor(a3, 32);
        // lane activates its own gate: p-index = kg -> gate id == tid
        float asel = (kg & 1) ? ((kg & 2) ? a3 : a1) : ((kg & 2) ? a2 : a0);
        float xsel = (kg & 1) ? ((kg & 2) ? xr.w : xr.y) : ((kg & 2) ? xr.z : xr.x);
        float gv = xsel + asel;
        act[tid] = is_tanh ? tanh_(gv) : sigm_(gv);
        __syncthreads();
        if (tid < DIM){
            float iv = act[tid];
            float fv = act[DIM + tid];
            float gg = act[2 * DIM + tid];
            float ov = act[3 * DIM + tid];
            c = fv * c + iv * gg;
            float h = ov * tanh_(c);
            hbuf[p ^ 1][(tid >> 5) * 36 + (tid & 31)] = h;
            hout[(size_t)t * DIM + tid] = h;
        }
        __syncthreads();
        xr = xn; p ^= 1;
    }
}

// ---------------- K4: LayerNorm -> bf16 ----------------
__global__ void k_ln(const float* __restrict__ hseq, const float* __restrict__ gamma,
                     const float* __restrict__ beta, __hip_bfloat16* __restrict__ hn){
    int wid = threadIdx.x >> 6;
    int lane = threadIdx.x & 63;
    int row = blockIdx.x * 4 + wid;
    float2 hv = ((const float2*)(hseq + (size_t)row * DIM))[lane];
    float s = hv.x + hv.y;
    float sq = fmaf(hv.x, hv.x, hv.y * hv.y);
    for (int off = 32; off; off >>= 1){ s += __shfl_xor(s, off); sq += __shfl_xor(sq, off); }
    float mu = s * (1.f / 128.f);
    float var = sq * (1.f / 128.f) - mu * mu;
    float inv = rsqrtf(var + 1e-5f);
    float2 gv = ((const float2*)gamma)[lane];
    float2 bv = ((const float2*)beta)[lane];
    __hip_bfloat162 pr;
    pr.x = __float2bfloat16((hv.x - mu) * inv * gv.x + bv.x);
    pr.y = __float2bfloat16((hv.y - mu) * inv * gv.y + bv.y);
    ((__hip_bfloat162*)hn)[(size_t)row * 64 + lane] = pr;
}

// ---------------- K5: head_W fp32 -> bf16 ----------------
__global__ void k_cvt(const float* __restrict__ w, __hip_bfloat16* __restrict__ wb){
    int i = blockIdx.x * blockDim.x + threadIdx.x;
    float4 v = ((const float4*)w)[i];
    __hip_bfloat162 p0, p1;
    p0.x = __float2bfloat16(v.x); p0.y = __float2bfloat16(v.y);
    p1.x = __float2bfloat16(v.z); p1.y = __float2bfloat16(v.w);
    ((__hip_bfloat162*)wb)[2 * i]     = p0;
    ((__hip_bfloat162*)wb)[2 * i + 1] = p1;
}

// ---------------- K6: head GEMM (bf16 MFMA, swapped operands, float4 stores) ----
__global__ __launch_bounds__(256) void k_head(const __hip_bfloat16* __restrict__ hn,
                                              const __hip_bfloat16* __restrict__ wb,
                                              const float* __restrict__ head_b,
                                              float* __restrict__ out){
    int bn = blockIdx.x;
    int bm = blockIdx.y;
    int wid = threadIdx.x >> 6;
    int lane = threadIdx.x & 63;
    int wr = wid >> 1, wc = wid & 1;
    int row0 = bm * 128 + wr * 64;
    int col0 = bn * 128 + wc * 64;
    const short* A  = (const short*)hn;   // [8192][128]
    const short* Bp = (const short*)wb;   // [32000][128]
    f32x4 zero = {0.f, 0.f, 0.f, 0.f};
    f32x4 acc[4][4];   // [mi][ni]
#pragma unroll
    for (int i = 0; i < 4; ++i)
#pragma unroll
        for (int j = 0; j < 4; ++j) acc[i][j] = zero;
    int lrow = lane & 15;
    int kgr = (lane >> 4) * 8;
#pragma unroll
    for (int ks = 0; ks < 4; ++ks){
        short8 a[4], bf[4];
#pragma unroll
        for (int mi = 0; mi < 4; ++mi)
            a[mi] = *(const short8*)(A + (size_t)(row0 + mi * 16 + lrow) * DIM + ks * 32 + kgr);
#pragma unroll
        for (int ni = 0; ni < 4; ++ni)
            bf[ni] = *(const short8*)(Bp + (size_t)(col0 + ni * 16 + lrow) * DIM + ks * 32 + kgr);
#pragma unroll
        for (int mi = 0; mi < 4; ++mi)
#pragma unroll
            for (int ni = 0; ni < 4; ++ni)
                acc[mi][ni] = __builtin_amdgcn_mfma_f32_16x16x32_bf16(bf[ni], a[mi], acc[mi][ni], 0, 0, 0);
    }
    int csub = (lane >> 4) * 4;
#pragma unroll
    for (int ni = 0; ni < 4; ++ni){
        int cbase = col0 + ni * 16 + csub;
        float4 b4 = ((const float4*)head_b)[cbase >> 2];
#pragma unroll
        for (int mi = 0; mi < 4; ++mi){
            int row = row0 + mi * 16 + lrow;
            float4 v;
            v.x = acc[mi][ni][0] + b4.x;
            v.y = acc[mi][ni][1] + b4.y;
            v.z = acc[mi][ni][2] + b4.z;
            v.w = acc[mi][ni][3] + b4.w;
            *(float4*)(out + (size_t)row * VOCAB + cbase) = v;
        }
    }
}

extern "C" void kernel_launch(void* const* d_in, const int* in_sizes, int n_in,
                              void* d_out, int out_size, void* d_ws, size_t ws_size,
                              hipStream_t stream){
    const int*   x     = (const int*)  d_in[0];
    const float* emb   = (const float*)d_in[1];
    const float* Wih   = (const float*)d_in[2];
    const float* Whh   = (const float*)d_in[3];
    const float* bih   = (const float*)d_in[4];
    const float* bhh   = (const float*)d_in[5];
    const float* gamma = (const float*)d_in[6];
    const float* beta  = (const float*)d_in[7];
    const float* headW = (const float*)d_in[8];
    const float* headb = (const float*)d_in[9];
    float* out = (float*)d_out;

    char* ws = (char*)d_ws;
    float* xw   = (float*)ws;                                  // 16 MB [8192][512] (permuted)
    float* hseq = (float*)(ws + (16u << 20));                  // 4 MB  [8192][128]
    __hip_bfloat16* hn = (__hip_bfloat16*)(ws + (20u << 20));  // 2 MB
    __hip_bfloat16* wb = (__hip_bfloat16*)(ws + (22u << 20));  // 8 MB

    k_embed<<<1024, 256, 0, stream>>>(x, emb, hseq);
    k_cvt  <<<4000, 256, 0, stream>>>(headW, wb);
    for (int l = 0; l < NL; ++l){
        k_xw  <<<256, 512, 0, stream>>>(hseq, Wih + (size_t)l * G4 * DIM,
                                        bih + l * G4, bhh + l * G4, xw);
        k_scan<<<32, 512, 0, stream>>>(xw, Whh + (size_t)l * G4 * DIM, hseq);
    }
    k_ln   <<<2048, 256, 0, stream>>>(hseq, gamma, beta, hn);
    k_head <<<dim3(250, 64), 256, 0, stream>>>(hn, wb, headb, out);
}